// Round 3
// baseline (430.795 us; speedup 1.0000x reference)
//
#include <hip/hip_runtime.h>
#include <hip/hip_bf16.h>

#define N_TOK 262144
#define D_FEAT 128
#define C_CLS 64
#define TILE_M 128
#define NBLOCKS 1024
#define BLOCK_T 256
#define NTILES (N_TOK / TILE_M)             // 2048
#define TILES_PER_BLOCK (NTILES / NBLOCKS)  // 2
#define NSTEP (TILES_PER_BLOCK * 2)         // 4 (16-row steps per wave)
#define SEG_ELEMS (C_CLS * D_FEAT)          // 8192
#define RED_BLOCKS 256
#define BCHUNK (NBLOCKS / 8)                // 128 slices per red-chunk

typedef __attribute__((ext_vector_type(8))) short bf16x8;
typedef __attribute__((ext_vector_type(4))) float f32x4;

__device__ __forceinline__ short f2bf(float x) {
    // scalar cast -> compiler fuses pairs into v_cvt_pk_bf16_f32 (RTNE)
    return (short)__bfloat16_as_ushort(__float2bfloat16(x));
}

__device__ __forceinline__ bf16x8 pack8(float4 a, float4 b) {
    bf16x8 t;
    t[0] = f2bf(a.x); t[1] = f2bf(a.y); t[2] = f2bf(a.z); t[3] = f2bf(a.w);
    t[4] = f2bf(b.x); t[5] = f2bf(b.y); t[6] = f2bf(b.z); t[7] = f2bf(b.w);
    return t;
}

// v4: single-pass over f (from v3) + NO-ATOMIC seg flush.
// MODE 1: each block stores its 32KB seg partial to a private ws slice with
//         plain dwordx4 stores; center_red reduces the slices (65K atomics
//         total instead of 8.4M memory-side RMWs into a 32KB region).
// MODE 0: fallback atomic flush when ws_size is too small.
template<int MODE>
__global__ __launch_bounds__(BLOCK_T, 4) void center_main(
    const float* __restrict__ f, const int* __restrict__ label,
    const float* __restrict__ centers, float* __restrict__ dist_out,
    float* __restrict__ ws_loss, unsigned* __restrict__ ws_cnt,
    float* __restrict__ ws_seg, float* __restrict__ ws_part)
{
    __shared__ float    seg[SEG_ELEMS];   // 32 KB fp32, col XOR-swizzled by (class&31)
    __shared__ float    c2s[C_CLS];
    __shared__ float    f2t[TILE_M];
    __shared__ int      lblt[TILES_PER_BLOCK][TILE_M];
    __shared__ unsigned cnts[C_CLS];

    const int tid  = threadIdx.x;
    const int lane = tid & 63;
    const int w    = tid >> 6;        // wave id 0..3
    const int qk   = lane >> 4;       // k-quad 0..3
    const int ln   = lane & 15;

    // ---- early global loads (issue before the setup barrier) ----
    // labels for both tiles: lanes 0-31 -> tile0 rows, lanes 32-63 -> tile1 rows
    const int tt = lane >> 5;
    const int lr = lane & 31;
    const int lv = label[(blockIdx.x + tt * NBLOCKS) * TILE_M + w * 32 + lr];

    // first 16-row step of f
    const float* ap0 = f + (size_t)(blockIdx.x * TILE_M + w * 32 + ln) * D_FEAT + qk * 8;
    float4 v[8];
    #pragma unroll
    for (int ks = 0; ks < 4; ++ks) {
        v[2*ks]   = *(const float4*)(ap0 + ks * 32);
        v[2*ks+1] = *(const float4*)(ap0 + ks * 32 + 4);
    }

    // ---- block setup ----
    for (int i = tid; i < SEG_ELEMS; i += BLOCK_T) seg[i] = 0.f;
    if (tid < C_CLS) {
        cnts[tid] = 0u;
        float s = 0.f;
        const float* cp = centers + tid * D_FEAT;
        for (int k = 0; k < D_FEAT; k += 4) {
            float4 c4 = *(const float4*)(cp + k);
            s += c4.x*c4.x + c4.y*c4.y + c4.z*c4.z + c4.w*c4.w;
        }
        c2s[tid] = s;
    }

    // B fragments (centers as bf16), in registers for the whole kernel.
    bf16x8 bfr[4][4];
    #pragma unroll
    for (int ct = 0; ct < 4; ++ct) {
        const float* bp = centers + (ct * 16 + ln) * D_FEAT + qk * 8;
        #pragma unroll
        for (int ks = 0; ks < 4; ++ks) {
            float4 v0 = *(const float4*)(bp + ks * 32);
            float4 v1 = *(const float4*)(bp + ks * 32 + 4);
            bfr[ct][ks] = pack8(v0, v1);
        }
    }
    __syncthreads();   // seg zero + cnts zero + c2s ready

    lblt[tt][w * 32 + lr] = lv;
    atomicAdd(&cnts[lv], 1u);

    float lossa = 0.f;

    #pragma unroll
    for (int t = 0; t < NSTEP; ++t) {
        const int half  = t & 1;
        const int tl    = t >> 1;
        const int gbase = (blockIdx.x + tl * NBLOCKS) * TILE_M + w * 32 + half * 16;

        // ---- prefetch next 16-row step while processing this one ----
        float4 vn[8];
        if (t + 1 < NSTEP) {
            const int t1 = t + 1;
            const float* an = f + (size_t)((blockIdx.x + (t1 >> 1) * NBLOCKS) * TILE_M
                                           + w * 32 + (t1 & 1) * 16 + ln) * D_FEAT + qk * 8;
            #pragma unroll
            for (int ks = 0; ks < 4; ++ks) {
                vn[2*ks]   = *(const float4*)(an + ks * 32);
                vn[2*ks+1] = *(const float4*)(an + ks * 32 + 4);
            }
        }

        // ---- f2 from registers ----
        float s2 = 0.f;
        #pragma unroll
        for (int i = 0; i < 8; ++i)
            s2 += v[i].x*v[i].x + v[i].y*v[i].y + v[i].z*v[i].z + v[i].w*v[i].w;
        s2 += __shfl_xor(s2, 16);
        s2 += __shfl_xor(s2, 32);
        if (lane < 16) f2t[w * 32 + half * 16 + lane] = s2;

        // ---- A fragments (bf16) from the same registers ----
        bf16x8 afr[4];
        #pragma unroll
        for (int ks = 0; ks < 4; ++ks) afr[ks] = pack8(v[2*ks], v[2*ks+1]);

        // ---- seg atomics from registers (label-XOR bank swizzle) ----
        {
            const int lb = lblt[tl][w * 32 + half * 16 + ln];
            const int sw = lb & 31;
            const int cb = lb << 7;
            const float* vf = (const float*)v;
            #pragma unroll
            for (int ks = 0; ks < 4; ++ks) {
                #pragma unroll
                for (int j = 0; j < 8; ++j)
                    atomicAdd(&seg[cb + ((ks * 32 + qk * 8 + j) ^ sw)], vf[ks * 8 + j]);
            }
        }

        // ---- MFMA + epilogue ----
        const int mloc = w * 32 + half * 16 + qk * 4;
        #pragma unroll
        for (int ct = 0; ct < 4; ++ct) {
            f32x4 acc = {0.f, 0.f, 0.f, 0.f};
            #pragma unroll
            for (int ks = 0; ks < 4; ++ks)
                acc = __builtin_amdgcn_mfma_f32_16x16x32_bf16(
                    afr[ks], bfr[ct][ks], acc, 0, 0, 0);
            const int n    = ct * 16 + ln;
            const float cv = c2s[n];
            float* op = dist_out + (size_t)(gbase + qk * 4) * C_CLS + n;
            #pragma unroll
            for (int u = 0; u < 4; ++u) {
                const float dv = f2t[mloc + u] + cv - 2.f * acc[u];
                op[(size_t)u * C_CLS] = dv;
                if (lblt[tl][mloc + u] == n) lossa += dv;
            }
        }

        if (t + 1 < NSTEP) {
            #pragma unroll
            for (int i = 0; i < 8; ++i) v[i] = vn[i];
        }
    }

    // ---- flush block partials ----
    __syncthreads();   // all waves' seg/cnts LDS atomics complete
    if (MODE == 1) {
        // plain dwordx4 stores to this block's private slice (unswizzled)
        float* dst = ws_part + (size_t)blockIdx.x * SEG_ELEMS;
        for (int i0 = tid * 4; i0 < SEG_ELEMS; i0 += BLOCK_T * 4) {
            const int c   = i0 >> 7;
            const int col = i0 & 127;
            const int sw  = c & 31;
            float4 o;
            o.x = seg[(c << 7) + ((col + 0) ^ sw)];
            o.y = seg[(c << 7) + ((col + 1) ^ sw)];
            o.z = seg[(c << 7) + ((col + 2) ^ sw)];
            o.w = seg[(c << 7) + ((col + 3) ^ sw)];
            *(float4*)(dst + i0) = o;
        }
    } else {
        for (int i = tid; i < SEG_ELEMS; i += BLOCK_T) {
            const int c   = i >> 7;
            const int col = i & 127;
            unsafeAtomicAdd(&ws_seg[i], seg[(c << 7) + (col ^ (c & 31))]);
        }
    }
    if (tid < C_CLS) atomicAdd(&ws_cnt[tid], cnts[tid]);
    #pragma unroll
    for (int off = 32; off; off >>= 1) lossa += __shfl_xor(lossa, off);
    if (lane == 0) unsafeAtomicAdd(ws_loss, lossa);
}

// Reduce 1024 partial slices -> ws_seg. 256 blocks: 8 b-chunks x 32 i-groups.
__global__ __launch_bounds__(256) void center_red(
    const float* __restrict__ ws_part, float* __restrict__ ws_seg)
{
    const int i  = (blockIdx.x & 31) * 256 + threadIdx.x;   // 0..8191
    const int c0 = (blockIdx.x >> 5) * BCHUNK;              // slice range start
    float s = 0.f;
    #pragma unroll 8
    for (int b = 0; b < BCHUNK; ++b)
        s += ws_part[(size_t)(c0 + b) * SEG_ELEMS + i];
    unsafeAtomicAdd(&ws_seg[i], s);   // 8 adds per address, 65K total
}

__global__ void center_fin(const float* __restrict__ centers,
                           const float* __restrict__ ws_loss,
                           const unsigned* __restrict__ ws_cnt,
                           const float* __restrict__ ws_seg,
                           float* __restrict__ out)
{
    const int i = blockIdx.x * 256 + threadIdx.x;
    if (i == 0) out[0] = ws_loss[0] / ((float)N_TOK * (float)D_FEAT);
    if (i < SEG_ELEMS) {
        const int c = i >> 7;
        const unsigned cnt = ws_cnt[c];
        const float denom = (float)(cnt > 1u ? cnt : 1u);
        out[1 + i] = ((float)cnt * centers[i] - ws_seg[i]) / denom;
    }
}

extern "C" void kernel_launch(void* const* d_in, const int* in_sizes, int n_in,
                              void* d_out, int out_size, void* d_ws, size_t ws_size,
                              hipStream_t stream)
{
    const float* f       = (const float*)d_in[0];
    const int*   lbl     = (const int*)d_in[1];
    const float* centers = (const float*)d_in[2];
    float* out = (float*)d_out;

    float*    ws_loss = (float*)d_ws;
    unsigned* ws_cnt  = (unsigned*)((char*)d_ws + 256);
    float*    ws_seg  = (float*)((char*)d_ws + 1024);
    float*    ws_part = (float*)((char*)d_ws + 1024 + SEG_ELEMS * sizeof(float));

    const size_t need = 1024 + SEG_ELEMS * sizeof(float)
                      + (size_t)NBLOCKS * SEG_ELEMS * sizeof(float);

    // zero the small accumulators (ws is poisoned 0xAA before every timed launch;
    // ws_part needs no zeroing: every slice is fully written before it is read)
    hipMemsetAsync(d_ws, 0, 1024 + SEG_ELEMS * sizeof(float), stream);

    float* dist_out = out + 1 + SEG_ELEMS;
    if (ws_size >= need) {
        center_main<1><<<NBLOCKS, BLOCK_T, 0, stream>>>(f, lbl, centers, dist_out,
                                                        ws_loss, ws_cnt, ws_seg, ws_part);
        center_red<<<RED_BLOCKS, 256, 0, stream>>>(ws_part, ws_seg);
    } else {
        center_main<0><<<NBLOCKS, BLOCK_T, 0, stream>>>(f, lbl, centers, dist_out,
                                                        ws_loss, ws_cnt, ws_seg, ws_part);
    }
    center_fin<<<32, 256, 0, stream>>>(centers, ws_loss, ws_cnt, ws_seg, out);
}

// Round 4
// 389.375 us; speedup vs baseline: 1.1064x; 1.1064x over previous
//
#include <hip/hip_runtime.h>
#include <hip/hip_bf16.h>

#define N_TOK 262144
#define D_FEAT 128
#define C_CLS 64
#define TILE_M 128                       // rows per tile (4 waves x 32)
#define NBLOCKS 1024
#define BLOCK_T 256
#define NTILES (N_TOK / TILE_M)          // 2048
#define TILES_PER_BLOCK (NTILES / NBLOCKS)  // 2
#define SEG_ELEMS (C_CLS * D_FEAT)       // 8192
#define RED_BLOCKS 256
#define BCHUNK (NBLOCKS / 8)             // 128 slices per red-chunk

typedef __attribute__((ext_vector_type(8))) short bf16x8;
typedef __attribute__((ext_vector_type(4))) float f32x4;

__device__ __forceinline__ short f2bf(float x) {
    return (short)__bfloat16_as_ushort(__float2bfloat16(x));   // RTNE
}

__device__ __forceinline__ bf16x8 pack8(float4 a, float4 b) {
    bf16x8 t;
    t[0] = f2bf(a.x); t[1] = f2bf(a.y); t[2] = f2bf(a.z); t[3] = f2bf(a.w);
    t[4] = f2bf(b.x); t[5] = f2bf(b.y); t[6] = f2bf(b.z); t[7] = f2bf(b.w);
    return t;
}

// v5 = round-2 body (84 VGPR, no spill, single pass over f) + ZERO high-contention
// global atomics:
//   seg  -> per-block 32KB slice, plain dwordx4 stores (swizzled), reduced in center_red
//   cnts -> per-block 64-uint slice, summed in center_red (512 atomics total)
//   loss -> per-block plain store, summed by center_red block 0
// MODE 0 fallback (small ws): old atomic flush.
template<int MODE>
__global__ __launch_bounds__(BLOCK_T, 4) void center_main(
    const float* __restrict__ f, const int* __restrict__ label,
    const float* __restrict__ centers, float* __restrict__ dist_out,
    float* __restrict__ ws_loss, unsigned* __restrict__ ws_cnt,
    float* __restrict__ ws_seg, float* __restrict__ ws_part,
    unsigned* __restrict__ ws_pcnt, float* __restrict__ ws_ploss)
{
    __shared__ float    seg[SEG_ELEMS];   // 32 KB fp32, col XOR-swizzled by (class&31)
    __shared__ float    c2s[C_CLS];
    __shared__ float    f2t[TILE_M];
    __shared__ int      lblt[TILE_M];
    __shared__ unsigned cnts[C_CLS];
    __shared__ float    wred[4];

    const int tid  = threadIdx.x;
    const int lane = tid & 63;
    const int w    = tid >> 6;        // wave id 0..3
    const int qk   = lane >> 4;       // k-quad 0..3
    const int ln   = lane & 15;

    // ---- block setup ----
    for (int i = tid; i < SEG_ELEMS; i += BLOCK_T) seg[i] = 0.f;
    if (tid < C_CLS) {
        cnts[tid] = 0u;
        float s = 0.f;
        const float* cp = centers + tid * D_FEAT;
        for (int k = 0; k < D_FEAT; k += 4) {
            float4 v = *(const float4*)(cp + k);
            s += v.x*v.x + v.y*v.y + v.z*v.z + v.w*v.w;
        }
        c2s[tid] = s;
    }

    // B fragments (centers as bf16), in registers for the whole kernel.
    // B[k][n]: lane holds n = ln, k = ks*32 + qk*8 + j
    bf16x8 bfr[4][4];
    #pragma unroll
    for (int ct = 0; ct < 4; ++ct) {
        const float* bp = centers + (ct * 16 + ln) * D_FEAT + qk * 8;
        #pragma unroll
        for (int ks = 0; ks < 4; ++ks) {
            float4 v0 = *(const float4*)(bp + ks * 32);
            float4 v1 = *(const float4*)(bp + ks * 32 + 4);
            bfr[ct][ks] = pack8(v0, v1);
        }
    }
    __syncthreads();   // seg zero + cnts zero + c2s ready

    float lossa = 0.f;

    for (int s = 0; s < TILES_PER_BLOCK; ++s) {
        const int tile = blockIdx.x + s * NBLOCKS;
        const int base = tile * TILE_M;
        const int row0 = base + w * 32;        // this wave's 32 rows

        // labels: one coalesced load per wave, staged to LDS (wave-private rows)
        if (lane < 32) {
            const int lv = label[row0 + lane];
            lblt[w * 32 + lane] = lv;
            atomicAdd(&cnts[lv], 1u);
        }

        #pragma unroll
        for (int rt = 0; rt < 2; ++rt) {
            const int rbase = row0 + rt * 16;
            // The ONLY read of these 16 rows: lane (qk,ln) loads row rbase+ln,
            // cols qk*8 + ks*32 + {0..7}  (8 x float4 = 32 floats/lane)
            const float* ap = f + (size_t)(rbase + ln) * D_FEAT + qk * 8;
            float4 v[8];
            #pragma unroll
            for (int ks = 0; ks < 4; ++ks) {
                v[2*ks]   = *(const float4*)(ap + ks * 32);
                v[2*ks+1] = *(const float4*)(ap + ks * 32 + 4);
            }

            // f2 from registers: lane partial, reduce across the 4 qk-groups
            float s2 = 0.f;
            #pragma unroll
            for (int i = 0; i < 8; ++i)
                s2 += v[i].x*v[i].x + v[i].y*v[i].y + v[i].z*v[i].z + v[i].w*v[i].w;
            s2 += __shfl_xor(s2, 16);
            s2 += __shfl_xor(s2, 32);
            if (lane < 16) f2t[w * 32 + rt * 16 + lane] = s2;   // row rbase+ln

            // A fragments (bf16) from the same registers
            bf16x8 afr[4];
            #pragma unroll
            for (int ks = 0; ks < 4; ++ks) afr[ks] = pack8(v[2*ks], v[2*ks+1]);

            // seg atomics from registers (label-XOR bank swizzle)
            {
                const int lb = lblt[w * 32 + rt * 16 + ln];
                const int sw = lb & 31;
                const int cb = lb << 7;
                const float* vf = (const float*)v;
                #pragma unroll
                for (int ks = 0; ks < 4; ++ks) {
                    #pragma unroll
                    for (int j = 0; j < 8; ++j)
                        atomicAdd(&seg[cb + ((ks * 32 + qk * 8 + j) ^ sw)], vf[ks * 8 + j]);
                }
            }

            // MFMA + epilogue
            const int mloc = w * 32 + rt * 16 + qk * 4;
            #pragma unroll
            for (int ct = 0; ct < 4; ++ct) {
                f32x4 acc = {0.f, 0.f, 0.f, 0.f};
                #pragma unroll
                for (int ks = 0; ks < 4; ++ks)
                    acc = __builtin_amdgcn_mfma_f32_16x16x32_bf16(
                        afr[ks], bfr[ct][ks], acc, 0, 0, 0);
                const int n    = ct * 16 + ln;
                const float cv = c2s[n];
                float* op = dist_out + (size_t)(rbase + qk * 4) * C_CLS + n;
                #pragma unroll
                for (int u = 0; u < 4; ++u) {
                    const float dv = f2t[mloc + u] + cv - 2.f * acc[u];
                    op[(size_t)u * C_CLS] = dv;
                    if (lblt[mloc + u] == n) lossa += dv;
                }
            }
        }
        // no per-tile barrier: f2t/lblt wave-private, seg/cnts atomic-only
    }

    // ---- flush block partials ----
    __syncthreads();   // all waves' seg/cnts LDS atomics complete
    if (MODE == 1) {
        // seg: linear copy (still swizzled) to this block's private slice
        float* dst = ws_part + (size_t)blockIdx.x * SEG_ELEMS;
        for (int i0 = tid * 4; i0 < SEG_ELEMS; i0 += BLOCK_T * 4)
            *(float4*)(dst + i0) = *(const float4*)(seg + i0);
        // counts: plain per-block store
        if (tid < C_CLS) ws_pcnt[blockIdx.x * C_CLS + tid] = cnts[tid];
        // loss: cross-wave LDS reduce, single plain store
        #pragma unroll
        for (int off = 32; off; off >>= 1) lossa += __shfl_xor(lossa, off);
        if (lane == 0) wred[w] = lossa;
        __syncthreads();
        if (tid == 0) ws_ploss[blockIdx.x] = wred[0] + wred[1] + wred[2] + wred[3];
    } else {
        for (int i = tid; i < SEG_ELEMS; i += BLOCK_T) {
            const int c   = i >> 7;
            const int col = i & 127;
            unsafeAtomicAdd(&ws_seg[i], seg[(c << 7) + (col ^ (c & 31))]);
        }
        if (tid < C_CLS) atomicAdd(&ws_cnt[tid], cnts[tid]);
        #pragma unroll
        for (int off = 32; off; off >>= 1) lossa += __shfl_xor(lossa, off);
        if (lane == 0) unsafeAtomicAdd(ws_loss, lossa);
    }
}

// Reduce 1024 partial slices -> ws_seg (unswizzling), counts, loss.
// 256 blocks: 8 slice-chunks x 32 element-groups.
__global__ __launch_bounds__(256) void center_red(
    const float* __restrict__ ws_part, const unsigned* __restrict__ ws_pcnt,
    const float* __restrict__ ws_ploss, float* __restrict__ ws_seg,
    unsigned* __restrict__ ws_cnt, float* __restrict__ ws_loss)
{
    __shared__ float lred[4];
    const int tid = threadIdx.x;
    const int i   = (blockIdx.x & 31) * 256 + tid;      // 0..8191 (swizzled space)
    const int c0  = (blockIdx.x >> 5) * BCHUNK;         // slice range start
    float s = 0.f;
    #pragma unroll 8
    for (int b = 0; b < BCHUNK; ++b)
        s += ws_part[(size_t)(c0 + b) * SEG_ELEMS + i];
    const int c    = i >> 7;
    const int scol = i & 127;
    unsafeAtomicAdd(&ws_seg[(c << 7) + (scol ^ (c & 31))], s);  // 8 adds/addr, spread

    if ((blockIdx.x & 31) == 0 && tid < C_CLS) {        // 8 blocks handle counts
        unsigned cs = 0u;
        #pragma unroll 8
        for (int b = 0; b < BCHUNK; ++b)
            cs += ws_pcnt[(c0 + b) * C_CLS + tid];
        atomicAdd(&ws_cnt[tid], cs);                    // 8 adds/counter
    }
    if (blockIdx.x == 0) {                              // loss: 1024 -> 1
        float ls = 0.f;
        #pragma unroll
        for (int k = tid; k < NBLOCKS; k += 256) ls += ws_ploss[k];
        #pragma unroll
        for (int off = 32; off; off >>= 1) ls += __shfl_xor(ls, off);
        if ((tid & 63) == 0) lred[tid >> 6] = ls;
        __syncthreads();
        if (tid == 0) ws_loss[0] = lred[0] + lred[1] + lred[2] + lred[3];
    }
}

__global__ void center_fin(const float* __restrict__ centers,
                           const float* __restrict__ ws_loss,
                           const unsigned* __restrict__ ws_cnt,
                           const float* __restrict__ ws_seg,
                           float* __restrict__ out)
{
    const int i = blockIdx.x * 256 + threadIdx.x;
    if (i == 0) out[0] = ws_loss[0] / ((float)N_TOK * (float)D_FEAT);
    if (i < SEG_ELEMS) {
        const int c = i >> 7;
        const unsigned cnt = ws_cnt[c];
        const float denom = (float)(cnt > 1u ? cnt : 1u);
        out[1 + i] = ((float)cnt * centers[i] - ws_seg[i]) / denom;
    }
}

extern "C" void kernel_launch(void* const* d_in, const int* in_sizes, int n_in,
                              void* d_out, int out_size, void* d_ws, size_t ws_size,
                              hipStream_t stream)
{
    const float* f       = (const float*)d_in[0];
    const int*   lbl     = (const int*)d_in[1];
    const float* centers = (const float*)d_in[2];
    float* out = (float*)d_out;

    float*    ws_loss  = (float*)d_ws;
    unsigned* ws_cnt   = (unsigned*)((char*)d_ws + 256);
    float*    ws_seg   = (float*)((char*)d_ws + 1024);
    char*     p        = (char*)d_ws + 1024 + SEG_ELEMS * sizeof(float);
    float*    ws_part  = (float*)p;                                   // 33.55 MB
    unsigned* ws_pcnt  = (unsigned*)(p + (size_t)NBLOCKS * SEG_ELEMS * sizeof(float));
    float*    ws_ploss = (float*)(p + (size_t)NBLOCKS * SEG_ELEMS * sizeof(float)
                                     + (size_t)NBLOCKS * C_CLS * sizeof(unsigned));

    const size_t need = 1024 + SEG_ELEMS * sizeof(float)
                      + (size_t)NBLOCKS * SEG_ELEMS * sizeof(float)
                      + (size_t)NBLOCKS * C_CLS * sizeof(unsigned)
                      + (size_t)NBLOCKS * sizeof(float);

    // zero the small accumulators only (slices are fully written before read)
    hipMemsetAsync(d_ws, 0, 1024 + SEG_ELEMS * sizeof(float), stream);

    float* dist_out = out + 1 + SEG_ELEMS;
    if (ws_size >= need) {
        center_main<1><<<NBLOCKS, BLOCK_T, 0, stream>>>(f, lbl, centers, dist_out,
            ws_loss, ws_cnt, ws_seg, ws_part, ws_pcnt, ws_ploss);
        center_red<<<RED_BLOCKS, 256, 0, stream>>>(ws_part, ws_pcnt, ws_ploss,
                                                   ws_seg, ws_cnt, ws_loss);
    } else {
        center_main<0><<<NBLOCKS, BLOCK_T, 0, stream>>>(f, lbl, centers, dist_out,
            ws_loss, ws_cnt, ws_seg, ws_part, ws_pcnt, ws_ploss);
    }
    center_fin<<<32, 256, 0, stream>>>(centers, ws_loss, ws_cnt, ws_seg, out);
}

// Round 5
// 373.196 us; speedup vs baseline: 1.1543x; 1.0434x over previous
//
#include <hip/hip_runtime.h>
#include <hip/hip_bf16.h>

#define N_TOK 262144
#define D_FEAT 128
#define C_CLS 64
#define TILE_M 128                       // rows per tile (4 waves x 32)
#define NBLOCKS 1024
#define BLOCK_T 256
#define NTILES (N_TOK / TILE_M)          // 2048
#define TILES_PER_BLOCK (NTILES / NBLOCKS)  // 2
#define NSTEP (TILES_PER_BLOCK * 2)      // 4 (16-row steps per wave)
#define SEG_ELEMS (C_CLS * D_FEAT)       // 8192
#define RED_BLOCKS 256
#define BCHUNK (NBLOCKS / 8)             // 128 slices per red-chunk

typedef __attribute__((ext_vector_type(8))) short bf16x8;
typedef __attribute__((ext_vector_type(4))) float f32x4;

__device__ __forceinline__ short f2bf(float x) {
    return (short)__bfloat16_as_ushort(__float2bfloat16(x));   // RTNE
}

__device__ __forceinline__ bf16x8 pack8(float4 a, float4 b) {
    bf16x8 t;
    t[0] = f2bf(a.x); t[1] = f2bf(a.y); t[2] = f2bf(a.z); t[3] = f2bf(a.w);
    t[4] = f2bf(b.x); t[5] = f2bf(b.y); t[6] = f2bf(b.z); t[7] = f2bf(b.w);
    return t;
}

__device__ __forceinline__ void gload_lds16(const float* g, float* l) {
    __builtin_amdgcn_global_load_lds(
        (const __attribute__((address_space(1))) void*)g,
        (__attribute__((address_space(3))) void*)l, 16, 0, 0);
}

// Issue 8 global_load_lds (16B) staging rows [rbase..rbase+15] x 128 floats
// into buf[16][128]. LDS dest is linear (HW: base + lane*16); the 16B-chunk
// XOR swizzle (chunk ^= row&7) is applied on the GLOBAL source address
// (rule #21: both-sides-or-neither). Reads apply the same XOR.
__device__ __forceinline__ void stage_issue(const float* __restrict__ f,
                                            int rbase, float* buf, int lane) {
    const int rl = lane >> 5;          // row within pair
    const int dc = lane & 31;          // dest chunk
    #pragma unroll
    for (int i = 0; i < 8; ++i) {
        const int r  = i * 2 + rl;
        const int sc = dc ^ (r & 7);   // swizzled source chunk
        gload_lds16(f + (size_t)(rbase + r) * D_FEAT + sc * 4,
                    buf + (i * 2) * D_FEAT);
    }
}

// v6: MLP fix. Per-wave private 8KB LDS staging via global_load_lds:
// next step's 8KB is in flight under the current step's compute, with NO
// register cost and NO in-loop barriers (waves free-run). Per CU: 2 blocks
// x 4 waves x 8KB ~= 64KB outstanding vs the ~9KB Little's-law requirement.
// Body after the LDS read is the proven R2/R4 math, bit-identical.
template<int MODE>
__global__ __launch_bounds__(BLOCK_T, 2) void center_main(
    const float* __restrict__ f, const int* __restrict__ label,
    const float* __restrict__ centers, float* __restrict__ dist_out,
    float* __restrict__ ws_loss, unsigned* __restrict__ ws_cnt,
    float* __restrict__ ws_seg, float* __restrict__ ws_part,
    unsigned* __restrict__ ws_pcnt, float* __restrict__ ws_ploss)
{
    __shared__ float    seg[SEG_ELEMS];      // 32 KB, col XOR-swizzled by (class&31)
    __shared__ float    stage[4][16][D_FEAT];// 32 KB: per-wave 8KB staging buffer
    __shared__ float    c2s[C_CLS];
    __shared__ float    f2t[TILE_M];
    __shared__ int      lblt[TILES_PER_BLOCK][TILE_M];
    __shared__ unsigned cnts[C_CLS];
    __shared__ float    wred[4];

    const int tid  = threadIdx.x;
    const int lane = tid & 63;
    const int w    = tid >> 6;        // wave id 0..3
    const int qk   = lane >> 4;       // k-quad 0..3
    const int ln   = lane & 15;

    float* buf = &stage[w][0][0];     // this wave's private staging buffer

    // ---- issue stage for step 0 immediately (completes under setup) ----
    stage_issue(f, blockIdx.x * TILE_M + w * 32, buf, lane);

    // labels for both tiles: lanes 0-31 -> tile0, 32-63 -> tile1 (held in reg)
    const int tt = lane >> 5;
    const int lr = lane & 31;
    const int lv = label[(blockIdx.x + tt * NBLOCKS) * TILE_M + w * 32 + lr];

    // ---- block setup ----
    for (int i = tid; i < SEG_ELEMS; i += BLOCK_T) seg[i] = 0.f;
    if (tid < C_CLS) {
        cnts[tid] = 0u;
        float s = 0.f;
        const float* cp = centers + tid * D_FEAT;
        for (int k = 0; k < D_FEAT; k += 4) {
            float4 c4 = *(const float4*)(cp + k);
            s += c4.x*c4.x + c4.y*c4.y + c4.z*c4.z + c4.w*c4.w;
        }
        c2s[tid] = s;
    }

    // B fragments (centers as bf16), in registers for the whole kernel.
    bf16x8 bfr[4][4];
    #pragma unroll
    for (int ct = 0; ct < 4; ++ct) {
        const float* bp = centers + (ct * 16 + ln) * D_FEAT + qk * 8;
        #pragma unroll
        for (int ks = 0; ks < 4; ++ks) {
            float4 v0 = *(const float4*)(bp + ks * 32);
            float4 v1 = *(const float4*)(bp + ks * 32 + 4);
            bfr[ct][ks] = pack8(v0, v1);
        }
    }
    __syncthreads();   // seg/cnts zero + c2s ready

    lblt[tt][w * 32 + lr] = lv;       // wave-private rows of both tiles
    atomicAdd(&cnts[lv], 1u);

    float lossa = 0.f;

    for (int t = 0; t < NSTEP; ++t) {
        const int tl    = t >> 1;
        const int half  = t & 1;
        const int rbase = (blockIdx.x + tl * NBLOCKS) * TILE_M + w * 32 + half * 16;

        // ---- wait for this step's staged tile (rule #18 fence pattern) ----
        asm volatile("s_waitcnt vmcnt(0)" ::: "memory");
        __builtin_amdgcn_sched_barrier(0);

        // ---- LDS -> regs: lane (qk,ln) = row ln, chunks (ks*8+qk*2+h)^ (ln&7) ----
        float4 v[8];
        #pragma unroll
        for (int ks = 0; ks < 4; ++ks) {
            const int g0 = ks * 8 + qk * 2;
            v[2*ks]   = *(const float4*)(buf + ln * D_FEAT + ((g0    ) ^ (ln & 7)) * 4);
            v[2*ks+1] = *(const float4*)(buf + ln * D_FEAT + ((g0 + 1) ^ (ln & 7)) * 4);
        }

        // ---- reads done -> safe to overwrite buffer with next stage ----
        asm volatile("s_waitcnt lgkmcnt(0)" ::: "memory");
        __builtin_amdgcn_sched_barrier(0);
        if (t + 1 < NSTEP) {
            const int t1 = t + 1;
            stage_issue(f, (blockIdx.x + (t1 >> 1) * NBLOCKS) * TILE_M
                           + w * 32 + (t1 & 1) * 16, buf, lane);
        }

        // ======== proven R2/R4 body (reads only v[]) ========
        // f2 from registers: lane partial, reduce across the 4 qk-groups
        float s2 = 0.f;
        #pragma unroll
        for (int i = 0; i < 8; ++i)
            s2 += v[i].x*v[i].x + v[i].y*v[i].y + v[i].z*v[i].z + v[i].w*v[i].w;
        s2 += __shfl_xor(s2, 16);
        s2 += __shfl_xor(s2, 32);
        if (lane < 16) f2t[w * 32 + half * 16 + lane] = s2;

        // A fragments (bf16) from the same registers
        bf16x8 afr[4];
        #pragma unroll
        for (int ks = 0; ks < 4; ++ks) afr[ks] = pack8(v[2*ks], v[2*ks+1]);

        // seg atomics from registers (label-XOR bank swizzle)
        {
            const int lb = lblt[tl][w * 32 + half * 16 + ln];
            const int sw = lb & 31;
            const int cb = lb << 7;
            const float* vf = (const float*)v;
            #pragma unroll
            for (int ks = 0; ks < 4; ++ks) {
                #pragma unroll
                for (int j = 0; j < 8; ++j)
                    atomicAdd(&seg[cb + ((ks * 32 + qk * 8 + j) ^ sw)], vf[ks * 8 + j]);
            }
        }

        // MFMA + epilogue
        const int mloc = w * 32 + half * 16 + qk * 4;
        #pragma unroll
        for (int ct = 0; ct < 4; ++ct) {
            f32x4 acc = {0.f, 0.f, 0.f, 0.f};
            #pragma unroll
            for (int ks = 0; ks < 4; ++ks)
                acc = __builtin_amdgcn_mfma_f32_16x16x32_bf16(
                    afr[ks], bfr[ct][ks], acc, 0, 0, 0);
            const int n    = ct * 16 + ln;
            const float cv = c2s[n];
            float* op = dist_out + (size_t)(rbase + qk * 4) * C_CLS + n;
            #pragma unroll
            for (int u = 0; u < 4; ++u) {
                const float dv = f2t[mloc + u] + cv - 2.f * acc[u];
                op[(size_t)u * C_CLS] = dv;
                if (lblt[tl][mloc + u] == n) lossa += dv;
            }
        }
        // no per-step barrier: everything is wave-private or LDS-atomic
    }

    // ---- flush block partials ----
    __syncthreads();   // all waves' seg/cnts LDS atomics complete
    if (MODE == 1) {
        float* dst = ws_part + (size_t)blockIdx.x * SEG_ELEMS;
        for (int i0 = tid * 4; i0 < SEG_ELEMS; i0 += BLOCK_T * 4)
            *(float4*)(dst + i0) = *(const float4*)(seg + i0);   // still swizzled
        if (tid < C_CLS) ws_pcnt[blockIdx.x * C_CLS + tid] = cnts[tid];
        #pragma unroll
        for (int off = 32; off; off >>= 1) lossa += __shfl_xor(lossa, off);
        if (lane == 0) wred[w] = lossa;
        __syncthreads();
        if (tid == 0) ws_ploss[blockIdx.x] = wred[0] + wred[1] + wred[2] + wred[3];
    } else {
        for (int i = tid; i < SEG_ELEMS; i += BLOCK_T) {
            const int c   = i >> 7;
            const int col = i & 127;
            unsafeAtomicAdd(&ws_seg[i], seg[(c << 7) + (col ^ (c & 31))]);
        }
        if (tid < C_CLS) atomicAdd(&ws_cnt[tid], cnts[tid]);
        #pragma unroll
        for (int off = 32; off; off >>= 1) lossa += __shfl_xor(lossa, off);
        if (lane == 0) unsafeAtomicAdd(ws_loss, lossa);
    }
}

// Reduce 1024 partial slices -> ws_seg (unswizzling), counts, loss.
__global__ __launch_bounds__(256) void center_red(
    const float* __restrict__ ws_part, const unsigned* __restrict__ ws_pcnt,
    const float* __restrict__ ws_ploss, float* __restrict__ ws_seg,
    unsigned* __restrict__ ws_cnt, float* __restrict__ ws_loss)
{
    __shared__ float lred[4];
    const int tid = threadIdx.x;
    const int i   = (blockIdx.x & 31) * 256 + tid;      // 0..8191 (swizzled space)
    const int c0  = (blockIdx.x >> 5) * BCHUNK;         // slice range start
    float s = 0.f;
    #pragma unroll 8
    for (int b = 0; b < BCHUNK; ++b)
        s += ws_part[(size_t)(c0 + b) * SEG_ELEMS + i];
    const int c    = i >> 7;
    const int scol = i & 127;
    unsafeAtomicAdd(&ws_seg[(c << 7) + (scol ^ (c & 31))], s);

    if ((blockIdx.x & 31) == 0 && tid < C_CLS) {
        unsigned cs = 0u;
        #pragma unroll 8
        for (int b = 0; b < BCHUNK; ++b)
            cs += ws_pcnt[(c0 + b) * C_CLS + tid];
        atomicAdd(&ws_cnt[tid], cs);
    }
    if (blockIdx.x == 0) {
        float ls = 0.f;
        #pragma unroll
        for (int k = tid; k < NBLOCKS; k += 256) ls += ws_ploss[k];
        #pragma unroll
        for (int off = 32; off; off >>= 1) ls += __shfl_xor(ls, off);
        if ((tid & 63) == 0) lred[tid >> 6] = ls;
        __syncthreads();
        if (tid == 0) ws_loss[0] = lred[0] + lred[1] + lred[2] + lred[3];
    }
}

__global__ void center_fin(const float* __restrict__ centers,
                           const float* __restrict__ ws_loss,
                           const unsigned* __restrict__ ws_cnt,
                           const float* __restrict__ ws_seg,
                           float* __restrict__ out)
{
    const int i = blockIdx.x * 256 + threadIdx.x;
    if (i == 0) out[0] = ws_loss[0] / ((float)N_TOK * (float)D_FEAT);
    if (i < SEG_ELEMS) {
        const int c = i >> 7;
        const unsigned cnt = ws_cnt[c];
        const float denom = (float)(cnt > 1u ? cnt : 1u);
        out[1 + i] = ((float)cnt * centers[i] - ws_seg[i]) / denom;
    }
}

extern "C" void kernel_launch(void* const* d_in, const int* in_sizes, int n_in,
                              void* d_out, int out_size, void* d_ws, size_t ws_size,
                              hipStream_t stream)
{
    const float* f       = (const float*)d_in[0];
    const int*   lbl     = (const int*)d_in[1];
    const float* centers = (const float*)d_in[2];
    float* out = (float*)d_out;

    float*    ws_loss  = (float*)d_ws;
    unsigned* ws_cnt   = (unsigned*)((char*)d_ws + 256);
    float*    ws_seg   = (float*)((char*)d_ws + 1024);
    char*     p        = (char*)d_ws + 1024 + SEG_ELEMS * sizeof(float);
    float*    ws_part  = (float*)p;                                   // 33.55 MB
    unsigned* ws_pcnt  = (unsigned*)(p + (size_t)NBLOCKS * SEG_ELEMS * sizeof(float));
    float*    ws_ploss = (float*)(p + (size_t)NBLOCKS * SEG_ELEMS * sizeof(float)
                                     + (size_t)NBLOCKS * C_CLS * sizeof(unsigned));

    const size_t need = 1024 + SEG_ELEMS * sizeof(float)
                      + (size_t)NBLOCKS * SEG_ELEMS * sizeof(float)
                      + (size_t)NBLOCKS * C_CLS * sizeof(unsigned)
                      + (size_t)NBLOCKS * sizeof(float);

    // zero the small accumulators only (slices are fully written before read)
    hipMemsetAsync(d_ws, 0, 1024 + SEG_ELEMS * sizeof(float), stream);

    float* dist_out = out + 1 + SEG_ELEMS;
    if (ws_size >= need) {
        center_main<1><<<NBLOCKS, BLOCK_T, 0, stream>>>(f, lbl, centers, dist_out,
            ws_loss, ws_cnt, ws_seg, ws_part, ws_pcnt, ws_ploss);
        center_red<<<RED_BLOCKS, 256, 0, stream>>>(ws_part, ws_pcnt, ws_ploss,
                                                   ws_seg, ws_cnt, ws_loss);
    } else {
        center_main<0><<<NBLOCKS, BLOCK_T, 0, stream>>>(f, lbl, centers, dist_out,
            ws_loss, ws_cnt, ws_seg, ws_part, ws_pcnt, ws_ploss);
    }
    center_fin<<<32, 256, 0, stream>>>(centers, ws_loss, ws_cnt, ws_seg, out);
}